// Round 1
// 869.224 us; speedup vs baseline: 1.2291x; 1.2291x over previous
//
#include <hip/hip_runtime.h>

typedef __bf16 bf16_t;
typedef __bf16 bf16x8 __attribute__((ext_vector_type(8)));
typedef float floatx4 __attribute__((ext_vector_type(4)));

// ---------------------------------------------------------------------------
// k1: x (f32) -> bf16
__global__ __launch_bounds__(256) void cvt_x(const float* __restrict__ x,
                                             bf16_t* __restrict__ xb) {
    int i = (blockIdx.x * 256 + threadIdx.x) * 4;
    float4 v = *(const float4*)&x[i];
    bf16_t* o = &xb[i];
    o[0] = (bf16_t)v.x; o[1] = (bf16_t)v.y; o[2] = (bf16_t)v.z; o[3] = (bf16_t)v.w;
}

// k2: weight [NH, D, H] f32 -> w_t [n*64+h][d] bf16   (NH=16, D=1024, H=64)
__global__ __launch_bounds__(256) void prep_w(const float* __restrict__ w,
                                              bf16_t* __restrict__ wt) {
    int o = blockIdx.x * 256 + threadIdx.x;      // over 1048576
    int d = o & 1023, nh = o >> 10;
    int n = nh >> 6, h = nh & 63;
    wt[o] = (bf16_t)w[(size_t)n * 65536 + (size_t)d * 64 + h];
}

// k3: lin_w [D][NH*H] f32 -> bf16 (already B^T layout for proj GEMM)
__global__ __launch_bounds__(256) void cvt_linw(const float* __restrict__ lw,
                                                bf16_t* __restrict__ lb) {
    int i = (blockIdx.x * 256 + threadIdx.x) * 4;
    float4 v = *(const float4*)&lw[i];
    bf16_t* o = &lb[i];
    o[0] = (bf16_t)v.x; o[1] = (bf16_t)v.y; o[2] = (bf16_t)v.z; o[3] = (bf16_t)v.w;
}

// ---------------------------------------------------------------------------
// Shared GEMM for stage A (logits) and stage D (output proj).
// C[8192,1024] = A[8192,1024] @ Bt[1024,1024]^T, 128x128 tile, 4 waves (2x2).
// mode 0: out_bf[idx] = bf16(acc)
// mode 1: out_f[idx] = acc + bias[col] + xres[idx]
__global__ __launch_bounds__(256) void gemm_ad(const bf16_t* __restrict__ A,
                                               const bf16_t* __restrict__ Bt,
                                               int mode,
                                               bf16_t* __restrict__ out_bf,
                                               float* __restrict__ out_f,
                                               const float* __restrict__ bias,
                                               const float* __restrict__ xres) {
    __shared__ __attribute__((aligned(16))) bf16_t As[128][40];
    __shared__ __attribute__((aligned(16))) bf16_t Bs[128][40];
    int tid = threadIdx.x;
    int bm = blockIdx.x * 128, bn = blockIdx.y * 128;
    int wave = tid >> 6, lane = tid & 63;
    int wm = (wave >> 1) * 64, wn = (wave & 1) * 64;
    int l15 = lane & 15, quad = lane >> 4;
    floatx4 acc[4][4] = {};
    const bf16_t* abase = A + (size_t)bm * 1024;
    const bf16_t* bbase = Bt + (size_t)bn * 1024;
    for (int kt = 0; kt < 1024; kt += 32) {
        __syncthreads();
        for (int i = 0; i < 2; i++) {
            int c = tid + i * 256;
            int r = c >> 2, c8 = (c & 3) * 8;
            *(bf16x8*)&As[r][c8] = *(const bf16x8*)&abase[(size_t)r * 1024 + kt + c8];
            *(bf16x8*)&Bs[r][c8] = *(const bf16x8*)&bbase[(size_t)r * 1024 + kt + c8];
        }
        __syncthreads();
        bf16x8 af[4], bfr[4];
        for (int mi = 0; mi < 4; mi++) af[mi] = *(const bf16x8*)&As[wm + mi * 16 + l15][quad * 8];
        for (int ni = 0; ni < 4; ni++) bfr[ni] = *(const bf16x8*)&Bs[wn + ni * 16 + l15][quad * 8];
        for (int mi = 0; mi < 4; mi++)
            for (int ni = 0; ni < 4; ni++)
                acc[mi][ni] = __builtin_amdgcn_mfma_f32_16x16x32_bf16(af[mi], bfr[ni], acc[mi][ni], 0, 0, 0);
    }
    for (int mi = 0; mi < 4; mi++)
        for (int ni = 0; ni < 4; ni++) {
            int col = bn + wn + ni * 16 + l15;
            for (int r = 0; r < 4; r++) {
                int row = bm + wm + mi * 16 + quad * 4 + r;
                size_t idx = (size_t)row * 1024 + col;
                float v = acc[mi][ni][r];
                if (mode == 0) out_bf[idx] = (bf16_t)v;
                else           out_f[idx] = v + bias[col] + xres[idx];
            }
        }
}

// ---------------------------------------------------------------------------
// k5: logits [b*1024+s][n*64+h] -> vt [(n*8+b)*64+h][s]  (V^T per head)
__global__ __launch_bounds__(256) void transpose_v(const bf16_t* __restrict__ logits,
                                                   bf16_t* __restrict__ vt) {
    __shared__ __attribute__((aligned(16))) bf16_t T[64][72];
    int nb = blockIdx.y;
    int n = nb >> 3, b = nb & 7;
    int s0 = blockIdx.x * 64;
    int tid = threadIdx.x;
    const bf16_t* src = logits + (size_t)(b * 1024 + s0) * 1024 + n * 64;
    for (int i = 0; i < 2; i++) {
        int c = tid + i * 256;
        int r = c >> 3, c8 = (c & 7) * 8;
        *(bf16x8*)&T[r][c8] = *(const bf16x8*)&src[(size_t)r * 1024 + c8];
    }
    __syncthreads();
    bf16_t* dst = vt + (size_t)nb * 64 * 1024 + s0;
    for (int i = 0; i < 2; i++) {
        int c = tid + i * 256;
        int h = c >> 3, sx = (c & 7) * 8;
        bf16x8 o;
        for (int j = 0; j < 8; j++) o[j] = T[sx + j][h];
        *(bf16x8*)&dst[(size_t)h * 1024 + sx] = o;
    }
}

// ---------------------------------------------------------------------------
// Fused scores -> softmax -> PV.  Per WG: one (n,b) head, 64 query rows.
// Pass 1: S = Q@K^T/8, accumulate row sums of exp(S) (no max subtraction:
//   scores bounded ~|q||k|/8 << 88, diagonal term guarantees sum >= 1).
// Pass 2: recompute S, write exp(S)/rowsum to attn (f32, written ONCE),
//   bounce normalized P through LDS (bf16), accumulate P@V into outh.
// Each wave owns 16 rows; 4 waves share Ks/Vts staging tiles.
// grid: x = row-tile (16 x 64 rows), y = nb (128).
__global__ __launch_bounds__(256) void fused_attn(const bf16_t* __restrict__ logits,
                                                  const bf16_t* __restrict__ vt,
                                                  float* __restrict__ attn,
                                                  bf16_t* __restrict__ outh) {
    __shared__ __attribute__((aligned(16))) bf16_t Qs[64][72];
    __shared__ __attribute__((aligned(16))) bf16_t Ks[128][72];
    __shared__ __attribute__((aligned(16))) bf16_t Vts[64][136];   // 272B stride: 16B-aligned, 2-way bank alias (free)
    __shared__ __attribute__((aligned(16))) bf16_t Pl[4][16][136]; // per-wave P bounce tile
    int nb = blockIdx.y;
    int n = nb >> 3, b = nb & 7;
    int r0 = blockIdx.x * 64;
    int tid = threadIdx.x;
    int wave = tid >> 6, lane = tid & 63;
    int l15 = lane & 15, quad = lane >> 4;
    const bf16_t* qbase = logits + (size_t)(b * 1024 + r0) * 1024 + n * 64;
    const bf16_t* kbase = logits + (size_t)(b * 1024) * 1024 + n * 64;
    const bf16_t* vbase = vt + (size_t)nb * 64 * 1024;

    // stage Q tile [64][64]
    for (int i = 0; i < 2; i++) {
        int c = tid + i * 256;
        int r = c >> 3, c8 = (c & 7) * 8;
        *(bf16x8*)&Qs[r][c8] = *(const bf16x8*)&qbase[(size_t)r * 1024 + c8];
    }

    float rsum[4] = {0.f, 0.f, 0.f, 0.f};
    // ---------------- pass 1: row sums of exp ----------------
    for (int t0 = 0; t0 < 1024; t0 += 128) {
        __syncthreads();
        for (int i = 0; i < 4; i++) {
            int c = tid + i * 256;
            int r = c >> 3, c8 = (c & 7) * 8;
            *(bf16x8*)&Ks[r][c8] = *(const bf16x8*)&kbase[(size_t)(t0 + r) * 1024 + c8];
        }
        __syncthreads();
        floatx4 acc[8] = {};
        for (int ks = 0; ks < 2; ks++) {
            bf16x8 a = *(const bf16x8*)&Qs[wave * 16 + l15][ks * 32 + quad * 8];
            for (int ni = 0; ni < 8; ni++) {
                bf16x8 bf = *(const bf16x8*)&Ks[ni * 16 + l15][ks * 32 + quad * 8];
                acc[ni] = __builtin_amdgcn_mfma_f32_16x16x32_bf16(a, bf, acc[ni], 0, 0, 0);
            }
        }
        for (int ni = 0; ni < 8; ni++)
            for (int r = 0; r < 4; r++)
                rsum[r] += __expf(acc[ni][r] * 0.125f);
    }
    // reduce over the 16-lane column group (rows are quad-local: no cross-wave reduce)
    for (int off = 1; off < 16; off <<= 1)
        for (int r = 0; r < 4; r++) rsum[r] += __shfl_xor(rsum[r], off);
    float inv[4];
    for (int r = 0; r < 4; r++) inv[r] = 1.0f / rsum[r];

    // ---------------- pass 2: normalize, write attn, PV ----------------
    floatx4 accpv[4] = {};
    float* obase = attn + (size_t)nb * 1048576 + (size_t)r0 * 1024;
    for (int t0 = 0; t0 < 1024; t0 += 128) {
        __syncthreads();
        for (int i = 0; i < 4; i++) {
            int c = tid + i * 256;
            int r = c >> 3, c8 = (c & 7) * 8;
            *(bf16x8*)&Ks[r][c8] = *(const bf16x8*)&kbase[(size_t)(t0 + r) * 1024 + c8];
        }
        for (int i = 0; i < 4; i++) {
            int c = tid + i * 256;
            int h = c >> 4, c8 = (c & 15) * 8;
            *(bf16x8*)&Vts[h][c8] = *(const bf16x8*)&vbase[(size_t)h * 1024 + t0 + c8];
        }
        __syncthreads();
        floatx4 acc[8] = {};
        for (int ks = 0; ks < 2; ks++) {
            bf16x8 a = *(const bf16x8*)&Qs[wave * 16 + l15][ks * 32 + quad * 8];
            for (int ni = 0; ni < 8; ni++) {
                bf16x8 bf = *(const bf16x8*)&Ks[ni * 16 + l15][ks * 32 + quad * 8];
                acc[ni] = __builtin_amdgcn_mfma_f32_16x16x32_bf16(a, bf, acc[ni], 0, 0, 0);
            }
        }
        for (int ni = 0; ni < 8; ni++)
            for (int r = 0; r < 4; r++) {
                float p = __expf(acc[ni][r] * 0.125f) * inv[r];
                int sl = wave * 16 + quad * 4 + r;
                obase[(size_t)sl * 1024 + t0 + ni * 16 + l15] = p;
                Pl[wave][quad * 4 + r][ni * 16 + l15] = (bf16_t)p;
            }
        // P (16 x 128) @ V (128 x 64) -> accumulate 16 x 64
        for (int ks2 = 0; ks2 < 4; ks2++) {
            bf16x8 pa = *(const bf16x8*)&Pl[wave][l15][ks2 * 32 + quad * 8];
            for (int ni = 0; ni < 4; ni++) {
                bf16x8 bv = *(const bf16x8*)&Vts[ni * 16 + l15][ks2 * 32 + quad * 8];
                accpv[ni] = __builtin_amdgcn_mfma_f32_16x16x32_bf16(pa, bv, accpv[ni], 0, 0, 0);
            }
        }
    }
    for (int ni = 0; ni < 4; ni++) {
        int h = ni * 16 + l15;
        for (int r = 0; r < 4; r++) {
            int s = r0 + wave * 16 + quad * 4 + r;
            outh[(size_t)(b * 1024 + s) * 1024 + n * 64 + h] = (bf16_t)accpv[ni][r];
        }
    }
}

// ---------------------------------------------------------------------------
// k10: LayerNorm over D=1024. grid = 8192 rows.
__global__ __launch_bounds__(256) void ln_kernel(const float* __restrict__ z,
                                                 const float* __restrict__ g,
                                                 const float* __restrict__ beta,
                                                 float* __restrict__ y) {
    size_t row = blockIdx.x;
    const float* p = z + row * 1024;
    int tid = threadIdx.x;
    float4 v = *(const float4*)&p[tid * 4];
    float s1 = v.x + v.y + v.z + v.w;
    float s2 = v.x * v.x + v.y * v.y + v.z * v.z + v.w * v.w;
    for (int off = 32; off; off >>= 1) {
        s1 += __shfl_xor(s1, off);
        s2 += __shfl_xor(s2, off);
    }
    __shared__ float r1[4], r2[4];
    int wave = tid >> 6;
    if ((tid & 63) == 0) { r1[wave] = s1; r2[wave] = s2; }
    __syncthreads();
    s1 = r1[0] + r1[1] + r1[2] + r1[3];
    s2 = r2[0] + r2[1] + r2[2] + r2[3];
    float mu = s1 * (1.0f / 1024.0f);
    float var = s2 * (1.0f / 1024.0f) - mu * mu;
    float rstd = rsqrtf(var + 1e-5f);
    float4 gv = *(const float4*)&g[tid * 4];
    float4 bv = *(const float4*)&beta[tid * 4];
    float4 o;
    o.x = (v.x - mu) * rstd * gv.x + bv.x;
    o.y = (v.y - mu) * rstd * gv.y + bv.y;
    o.z = (v.z - mu) * rstd * gv.z + bv.z;
    o.w = (v.w - mu) * rstd * gv.w + bv.w;
    *(float4*)&y[row * 1024 + tid * 4] = o;
}

// ---------------------------------------------------------------------------
extern "C" void kernel_launch(void* const* d_in, const int* in_sizes, int n_in,
                              void* d_out, int out_size, void* d_ws, size_t ws_size,
                              hipStream_t stream) {
    const float* x     = (const float*)d_in[0];  // [8,1024,1024]
    const float* w     = (const float*)d_in[1];  // [16,1024,64]
    const float* lw    = (const float*)d_in[2];  // [1024,1024]
    const float* lb    = (const float*)d_in[3];  // [1024]
    const float* lg    = (const float*)d_in[4];  // [1024]
    const float* lbeta = (const float*)d_in[5];  // [1024]
    float* y    = (float*)d_out;                 // [8,1024,1024]
    float* attn = y + 8388608;                   // [128,1024,1024]

    // Workspace overlay (54.5 MB total):
    //   [0,16M)     xb (stage A input)   -> reused as outh (fused output)
    //   [16M,18M)   w_t
    //   [18M,20M)   lin_w bf16
    //   [20M,37M)   logits bf16          -> reused as lower half of z
    //   [37M,53M)   vt                   -> reused as upper half of z
    char* ws = (char*)d_ws;
    bf16_t* xb     = (bf16_t*)(ws);
    bf16_t* outh   = (bf16_t*)(ws);
    bf16_t* wt     = (bf16_t*)(ws + 16777216);
    bf16_t* lwb    = (bf16_t*)(ws + 18874368);
    bf16_t* logits = (bf16_t*)(ws + 20971520);
    float*  z      = (float*)(ws + 20971520);
    bf16_t* vt     = (bf16_t*)(ws + 37748736);

    hipLaunchKernelGGL(cvt_x,        dim3(8192),       dim3(256), 0, stream, x, xb);
    hipLaunchKernelGGL(prep_w,       dim3(4096),       dim3(256), 0, stream, w, wt);
    hipLaunchKernelGGL(cvt_linw,     dim3(1024),       dim3(256), 0, stream, lw, lwb);
    hipLaunchKernelGGL(gemm_ad,      dim3(64, 8),      dim3(256), 0, stream,
                       xb, wt, 0, logits, (float*)nullptr, (const float*)nullptr, (const float*)nullptr);
    hipLaunchKernelGGL(transpose_v,  dim3(16, 128),    dim3(256), 0, stream, logits, vt);
    hipLaunchKernelGGL(fused_attn,   dim3(16, 128),    dim3(256), 0, stream, logits, vt, attn, outh);
    hipLaunchKernelGGL(gemm_ad,      dim3(64, 8),      dim3(256), 0, stream,
                       outh, lwb, 1, (bf16_t*)nullptr, z, lb, x);
    hipLaunchKernelGGL(ln_kernel,    dim3(8192),       dim3(256), 0, stream, z, lg, lbeta, y);
}

// Round 2
// 858.308 us; speedup vs baseline: 1.2447x; 1.0127x over previous
//
#include <hip/hip_runtime.h>

typedef __bf16 bf16_t;
typedef __bf16 bf16x8 __attribute__((ext_vector_type(8)));
typedef float floatx4 __attribute__((ext_vector_type(4)));

#define GLD_LDS16(g, l) \
    __builtin_amdgcn_global_load_lds((const __attribute__((address_space(1))) void*)(g), \
                                     (__attribute__((address_space(3))) void*)(l), 16, 0, 0)

// ---------------------------------------------------------------------------
// k1: x (f32) -> bf16
__global__ __launch_bounds__(256) void cvt_x(const float* __restrict__ x,
                                             bf16_t* __restrict__ xb) {
    int i = (blockIdx.x * 256 + threadIdx.x) * 4;
    float4 v = *(const float4*)&x[i];
    bf16_t* o = &xb[i];
    o[0] = (bf16_t)v.x; o[1] = (bf16_t)v.y; o[2] = (bf16_t)v.z; o[3] = (bf16_t)v.w;
}

// k2: weight [NH, D, H] f32 -> w_t [n*64+h][d] bf16   (NH=16, D=1024, H=64)
__global__ __launch_bounds__(256) void prep_w(const float* __restrict__ w,
                                              bf16_t* __restrict__ wt) {
    int o = blockIdx.x * 256 + threadIdx.x;      // over 1048576
    int d = o & 1023, nh = o >> 10;
    int n = nh >> 6, h = nh & 63;
    wt[o] = (bf16_t)w[(size_t)n * 65536 + (size_t)d * 64 + h];
}

// k3: lin_w [D][NH*H] f32 -> bf16 (already B^T layout for proj GEMM)
__global__ __launch_bounds__(256) void cvt_linw(const float* __restrict__ lw,
                                                bf16_t* __restrict__ lb) {
    int i = (blockIdx.x * 256 + threadIdx.x) * 4;
    float4 v = *(const float4*)&lw[i];
    bf16_t* o = &lb[i];
    o[0] = (bf16_t)v.x; o[1] = (bf16_t)v.y; o[2] = (bf16_t)v.z; o[3] = (bf16_t)v.w;
}

// ---------------------------------------------------------------------------
// Shared GEMM for stage A (logits) and stage D (output proj).
// C[8192,1024] = A[8192,1024] @ Bt[1024,1024]^T, 128x128 tile, 4 waves (2x2).
// m97-style: global_load_lds width=16 into LINEAR [128][64] LDS with the
// rule-#21 both-sides XOR swizzle (byte ^= (row&7)<<4): inverse-swizzled
// global SOURCE column + swizzled ds_read -> conflict-optimal b128 reads.
// mode 0: out_bf[idx] = bf16(acc)
// mode 1: out_f[idx] = acc + bias[col] + xres[idx]
__global__ __launch_bounds__(256) void gemm_ad(const bf16_t* __restrict__ A,
                                               const bf16_t* __restrict__ Bt,
                                               int mode,
                                               bf16_t* __restrict__ out_bf,
                                               float* __restrict__ out_f,
                                               const float* __restrict__ bias,
                                               const float* __restrict__ xres) {
    __shared__ __attribute__((aligned(16))) bf16_t As[128][64];
    __shared__ __attribute__((aligned(16))) bf16_t Bs[128][64];
    int tid = threadIdx.x;
    int bm = blockIdx.x * 128, bn = blockIdx.y * 128;
    int wave = tid >> 6, lane = tid & 63;
    int wm = (wave >> 1) * 64, wn = (wave & 1) * 64;
    int l15 = lane & 15, quad = lane >> 4;
    floatx4 acc[4][4] = {};
    // staging: 16 segments of 1024B (8 rows) per tile; wave owns segs wave*4..+3.
    // lane's LDS slot (linear) = seg*1024 + lane*16 -> (row=seg*8+lane/8, colbyte=(lane&7)*16)
    // data placed there must be global column colbyte ^ ((row&7)<<4):
    int srow = lane >> 3;                    // row within segment == row&7
    int scol = 8 * ((lane & 7) ^ srow);      // inverse-swizzled source column (elems)
    const bf16_t* abase = A  + (size_t)bm * 1024;
    const bf16_t* bbase = Bt + (size_t)bn * 1024;
    for (int kt = 0; kt < 1024; kt += 64) {
        __syncthreads();
        for (int i = 0; i < 4; i++) {
            int seg = wave * 4 + i;
            int r = seg * 8 + srow;
            GLD_LDS16(abase + (size_t)r * 1024 + kt + scol, (char*)&As[0][0] + seg * 1024);
            GLD_LDS16(bbase + (size_t)r * 1024 + kt + scol, (char*)&Bs[0][0] + seg * 1024);
        }
        __syncthreads();
        for (int ks = 0; ks < 2; ks++) {
            bf16x8 af[4], bfr[4];
            for (int mi = 0; mi < 4; mi++) {
                int row = wm + mi * 16 + l15;
                int cb = (ks * 64 + quad * 16) ^ ((row & 7) << 4);
                af[mi] = *(const bf16x8*)((const char*)&As[row][0] + cb);
            }
            for (int ni = 0; ni < 4; ni++) {
                int row = wn + ni * 16 + l15;
                int cb = (ks * 64 + quad * 16) ^ ((row & 7) << 4);
                bfr[ni] = *(const bf16x8*)((const char*)&Bs[row][0] + cb);
            }
            for (int mi = 0; mi < 4; mi++)
                for (int ni = 0; ni < 4; ni++)
                    acc[mi][ni] = __builtin_amdgcn_mfma_f32_16x16x32_bf16(af[mi], bfr[ni], acc[mi][ni], 0, 0, 0);
        }
    }
    for (int mi = 0; mi < 4; mi++)
        for (int ni = 0; ni < 4; ni++) {
            int col = bn + wn + ni * 16 + l15;
            for (int r = 0; r < 4; r++) {
                int row = bm + wm + mi * 16 + quad * 4 + r;
                size_t idx = (size_t)row * 1024 + col;
                float v = acc[mi][ni][r];
                if (mode == 0) out_bf[idx] = (bf16_t)v;
                else           out_f[idx] = v + bias[col] + xres[idx];
            }
        }
}

// ---------------------------------------------------------------------------
// k5: logits [b*1024+s][n*64+h] -> vt [(n*8+b)*64+h][s]  (V^T per head)
__global__ __launch_bounds__(256) void transpose_v(const bf16_t* __restrict__ logits,
                                                   bf16_t* __restrict__ vt) {
    __shared__ __attribute__((aligned(16))) bf16_t T[64][72];
    int nb = blockIdx.y;
    int n = nb >> 3, b = nb & 7;
    int s0 = blockIdx.x * 64;
    int tid = threadIdx.x;
    const bf16_t* src = logits + (size_t)(b * 1024 + s0) * 1024 + n * 64;
    for (int i = 0; i < 2; i++) {
        int c = tid + i * 256;
        int r = c >> 3, c8 = (c & 7) * 8;
        *(bf16x8*)&T[r][c8] = *(const bf16x8*)&src[(size_t)r * 1024 + c8];
    }
    __syncthreads();
    bf16_t* dst = vt + (size_t)nb * 64 * 1024 + s0;
    for (int i = 0; i < 2; i++) {
        int c = tid + i * 256;
        int h = c >> 3, sx = (c & 7) * 8;
        bf16x8 o;
        for (int j = 0; j < 8; j++) o[j] = T[sx + j][h];
        *(bf16x8*)&dst[(size_t)h * 1024 + sx] = o;
    }
}

// ---------------------------------------------------------------------------
// Fused scores -> softmax -> PV.  Per WG: one (n,b) head, 64 query rows.
// Pass 1: S = Q@K^T/8, accumulate row sums of exp(S) (no max subtraction:
//   scores bounded ~|q||k|/8 << 88, diagonal term guarantees sum >= 1).
// Pass 2: recompute S, write exp(S)/rowsum to attn (f32, written ONCE),
//   bounce normalized P through LDS (bf16), accumulate P@V into outh.
// Each wave owns 16 rows; 4 waves share Ks/Vts staging tiles.
// grid: x = row-tile (16 x 64 rows), y = nb (128).
__global__ __launch_bounds__(256) void fused_attn(const bf16_t* __restrict__ logits,
                                                  const bf16_t* __restrict__ vt,
                                                  float* __restrict__ attn,
                                                  bf16_t* __restrict__ outh) {
    __shared__ __attribute__((aligned(16))) bf16_t Qs[64][72];
    __shared__ __attribute__((aligned(16))) bf16_t Ks[128][72];
    __shared__ __attribute__((aligned(16))) bf16_t Vts[64][136];   // 272B stride: 16B-aligned, 2-way bank alias (free)
    __shared__ __attribute__((aligned(16))) bf16_t Pl[4][16][136]; // per-wave P bounce tile
    int nb = blockIdx.y;
    int n = nb >> 3, b = nb & 7;
    int r0 = blockIdx.x * 64;
    int tid = threadIdx.x;
    int wave = tid >> 6, lane = tid & 63;
    int l15 = lane & 15, quad = lane >> 4;
    const bf16_t* qbase = logits + (size_t)(b * 1024 + r0) * 1024 + n * 64;
    const bf16_t* kbase = logits + (size_t)(b * 1024) * 1024 + n * 64;
    const bf16_t* vbase = vt + (size_t)nb * 64 * 1024;

    // stage Q tile [64][64]
    for (int i = 0; i < 2; i++) {
        int c = tid + i * 256;
        int r = c >> 3, c8 = (c & 7) * 8;
        *(bf16x8*)&Qs[r][c8] = *(const bf16x8*)&qbase[(size_t)r * 1024 + c8];
    }

    float rsum[4] = {0.f, 0.f, 0.f, 0.f};
    // ---------------- pass 1: row sums of exp ----------------
    for (int t0 = 0; t0 < 1024; t0 += 128) {
        __syncthreads();
        for (int i = 0; i < 4; i++) {
            int c = tid + i * 256;
            int r = c >> 3, c8 = (c & 7) * 8;
            *(bf16x8*)&Ks[r][c8] = *(const bf16x8*)&kbase[(size_t)(t0 + r) * 1024 + c8];
        }
        __syncthreads();
        floatx4 acc[8] = {};
        for (int ks = 0; ks < 2; ks++) {
            bf16x8 a = *(const bf16x8*)&Qs[wave * 16 + l15][ks * 32 + quad * 8];
            for (int ni = 0; ni < 8; ni++) {
                bf16x8 bf = *(const bf16x8*)&Ks[ni * 16 + l15][ks * 32 + quad * 8];
                acc[ni] = __builtin_amdgcn_mfma_f32_16x16x32_bf16(a, bf, acc[ni], 0, 0, 0);
            }
        }
        for (int ni = 0; ni < 8; ni++)
            for (int r = 0; r < 4; r++)
                rsum[r] += __expf(acc[ni][r] * 0.125f);
    }
    // reduce over the 16-lane column group (rows are quad-local: no cross-wave reduce)
    for (int off = 1; off < 16; off <<= 1)
        for (int r = 0; r < 4; r++) rsum[r] += __shfl_xor(rsum[r], off);
    float inv[4];
    for (int r = 0; r < 4; r++) inv[r] = 1.0f / rsum[r];

    // ---------------- pass 2: normalize, write attn, PV ----------------
    floatx4 accpv[4] = {};
    float* obase = attn + (size_t)nb * 1048576 + (size_t)r0 * 1024;
    for (int t0 = 0; t0 < 1024; t0 += 128) {
        __syncthreads();
        for (int i = 0; i < 4; i++) {
            int c = tid + i * 256;
            int r = c >> 3, c8 = (c & 7) * 8;
            *(bf16x8*)&Ks[r][c8] = *(const bf16x8*)&kbase[(size_t)(t0 + r) * 1024 + c8];
        }
        for (int i = 0; i < 4; i++) {
            int c = tid + i * 256;
            int h = c >> 4, c8 = (c & 15) * 8;
            *(bf16x8*)&Vts[h][c8] = *(const bf16x8*)&vbase[(size_t)h * 1024 + t0 + c8];
        }
        __syncthreads();
        floatx4 acc[8] = {};
        for (int ks = 0; ks < 2; ks++) {
            bf16x8 a = *(const bf16x8*)&Qs[wave * 16 + l15][ks * 32 + quad * 8];
            for (int ni = 0; ni < 8; ni++) {
                bf16x8 bf = *(const bf16x8*)&Ks[ni * 16 + l15][ks * 32 + quad * 8];
                acc[ni] = __builtin_amdgcn_mfma_f32_16x16x32_bf16(a, bf, acc[ni], 0, 0, 0);
            }
        }
        for (int ni = 0; ni < 8; ni++)
            for (int r = 0; r < 4; r++) {
                float p = __expf(acc[ni][r] * 0.125f) * inv[r];
                int sl = wave * 16 + quad * 4 + r;
                obase[(size_t)sl * 1024 + t0 + ni * 16 + l15] = p;
                Pl[wave][quad * 4 + r][ni * 16 + l15] = (bf16_t)p;
            }
        // P (16 x 128) @ V (128 x 64) -> accumulate 16 x 64
        for (int ks2 = 0; ks2 < 4; ks2++) {
            bf16x8 pa = *(const bf16x8*)&Pl[wave][l15][ks2 * 32 + quad * 8];
            for (int ni = 0; ni < 4; ni++) {
                bf16x8 bv = *(const bf16x8*)&Vts[ni * 16 + l15][ks2 * 32 + quad * 8];
                accpv[ni] = __builtin_amdgcn_mfma_f32_16x16x32_bf16(pa, bv, accpv[ni], 0, 0, 0);
            }
        }
    }
    for (int ni = 0; ni < 4; ni++) {
        int h = ni * 16 + l15;
        for (int r = 0; r < 4; r++) {
            int s = r0 + wave * 16 + quad * 4 + r;
            outh[(size_t)(b * 1024 + s) * 1024 + n * 64 + h] = (bf16_t)accpv[ni][r];
        }
    }
}

// ---------------------------------------------------------------------------
// k10: LayerNorm over D=1024. grid = 8192 rows.
__global__ __launch_bounds__(256) void ln_kernel(const float* __restrict__ z,
                                                 const float* __restrict__ g,
                                                 const float* __restrict__ beta,
                                                 float* __restrict__ y) {
    size_t row = blockIdx.x;
    const float* p = z + row * 1024;
    int tid = threadIdx.x;
    float4 v = *(const float4*)&p[tid * 4];
    float s1 = v.x + v.y + v.z + v.w;
    float s2 = v.x * v.x + v.y * v.y + v.z * v.z + v.w * v.w;
    for (int off = 32; off; off >>= 1) {
        s1 += __shfl_xor(s1, off);
        s2 += __shfl_xor(s2, off);
    }
    __shared__ float r1[4], r2[4];
    int wave = tid >> 6;
    if ((tid & 63) == 0) { r1[wave] = s1; r2[wave] = s2; }
    __syncthreads();
    s1 = r1[0] + r1[1] + r1[2] + r1[3];
    s2 = r2[0] + r2[1] + r2[2] + r2[3];
    float mu = s1 * (1.0f / 1024.0f);
    float var = s2 * (1.0f / 1024.0f) - mu * mu;
    float rstd = rsqrtf(var + 1e-5f);
    float4 gv = *(const float4*)&g[tid * 4];
    float4 bv = *(const float4*)&beta[tid * 4];
    float4 o;
    o.x = (v.x - mu) * rstd * gv.x + bv.x;
    o.y = (v.y - mu) * rstd * gv.y + bv.y;
    o.z = (v.z - mu) * rstd * gv.z + bv.z;
    o.w = (v.w - mu) * rstd * gv.w + bv.w;
    *(float4*)&y[row * 1024 + tid * 4] = o;
}

// ---------------------------------------------------------------------------
extern "C" void kernel_launch(void* const* d_in, const int* in_sizes, int n_in,
                              void* d_out, int out_size, void* d_ws, size_t ws_size,
                              hipStream_t stream) {
    const float* x     = (const float*)d_in[0];  // [8,1024,1024]
    const float* w     = (const float*)d_in[1];  // [16,1024,64]
    const float* lw    = (const float*)d_in[2];  // [1024,1024]
    const float* lb    = (const float*)d_in[3];  // [1024]
    const float* lg    = (const float*)d_in[4];  // [1024]
    const float* lbeta = (const float*)d_in[5];  // [1024]
    float* y    = (float*)d_out;                 // [8,1024,1024]
    float* attn = y + 8388608;                   // [128,1024,1024]

    // Workspace overlay (54.5 MB total):
    //   [0,16M)     xb (stage A input)   -> reused as outh (fused output)
    //   [16M,18M)   w_t
    //   [18M,20M)   lin_w bf16
    //   [20M,37M)   logits bf16          -> reused as lower half of z
    //   [37M,53M)   vt                   -> reused as upper half of z
    char* ws = (char*)d_ws;
    bf16_t* xb     = (bf16_t*)(ws);
    bf16_t* outh   = (bf16_t*)(ws);
    bf16_t* wt     = (bf16_t*)(ws + 16777216);
    bf16_t* lwb    = (bf16_t*)(ws + 18874368);
    bf16_t* logits = (bf16_t*)(ws + 20971520);
    float*  z      = (float*)(ws + 20971520);
    bf16_t* vt     = (bf16_t*)(ws + 37748736);

    hipLaunchKernelGGL(cvt_x,        dim3(8192),       dim3(256), 0, stream, x, xb);
    hipLaunchKernelGGL(prep_w,       dim3(4096),       dim3(256), 0, stream, w, wt);
    hipLaunchKernelGGL(cvt_linw,     dim3(1024),       dim3(256), 0, stream, lw, lwb);
    hipLaunchKernelGGL(gemm_ad,      dim3(64, 8),      dim3(256), 0, stream,
                       xb, wt, 0, logits, (float*)nullptr, (const float*)nullptr, (const float*)nullptr);
    hipLaunchKernelGGL(transpose_v,  dim3(16, 128),    dim3(256), 0, stream, logits, vt);
    hipLaunchKernelGGL(fused_attn,   dim3(16, 128),    dim3(256), 0, stream, logits, vt, attn, outh);
    hipLaunchKernelGGL(gemm_ad,      dim3(64, 8),      dim3(256), 0, stream,
                       outh, lwb, 1, (bf16_t*)nullptr, z, lb, x);
    hipLaunchKernelGGL(ln_kernel,    dim3(8192),       dim3(256), 0, stream, z, lg, lbeta, y);
}

// Round 3
// 852.098 us; speedup vs baseline: 1.2538x; 1.0073x over previous
//
#include <hip/hip_runtime.h>

typedef __bf16 bf16_t;
typedef __bf16 bf16x8 __attribute__((ext_vector_type(8)));
typedef float floatx4 __attribute__((ext_vector_type(4)));

#define GLD_LDS16(g, l) \
    __builtin_amdgcn_global_load_lds((const __attribute__((address_space(1))) void*)(g), \
                                     (__attribute__((address_space(3))) void*)(l), 16, 0, 0)

// ---------------------------------------------------------------------------
// k1: x (f32) -> bf16
__global__ __launch_bounds__(256) void cvt_x(const float* __restrict__ x,
                                             bf16_t* __restrict__ xb) {
    int i = (blockIdx.x * 256 + threadIdx.x) * 4;
    float4 v = *(const float4*)&x[i];
    bf16_t* o = &xb[i];
    o[0] = (bf16_t)v.x; o[1] = (bf16_t)v.y; o[2] = (bf16_t)v.z; o[3] = (bf16_t)v.w;
}

// k2: weight [NH, D, H] f32 -> w_t [n*64+h][d] bf16  (coalesced LDS transpose)
// grid: x = d-tile (16 x 64), y = n (16). One 64(d) x 64(h) tile per block.
__global__ __launch_bounds__(256) void prep_w(const float* __restrict__ w,
                                              bf16_t* __restrict__ wt) {
    __shared__ bf16_t Tb[64][72];
    int n = blockIdx.y, d0 = blockIdx.x * 64;
    int tid = threadIdx.x;
    const float* src = w + (size_t)n * 65536 + (size_t)d0 * 64;
    for (int i = 0; i < 4; i++) {
        int c = tid + i * 256;                 // 1024 float4 chunks
        int r = c >> 4, c4 = (c & 15) * 4;     // r = d-row, c4 = h-col
        float4 v = *(const float4*)&src[(size_t)r * 64 + c4];
        Tb[r][c4 + 0] = (bf16_t)v.x; Tb[r][c4 + 1] = (bf16_t)v.y;
        Tb[r][c4 + 2] = (bf16_t)v.z; Tb[r][c4 + 3] = (bf16_t)v.w;
    }
    __syncthreads();
    bf16_t* dst = wt + (size_t)(n * 64) * 1024 + d0;
    for (int i = 0; i < 2; i++) {
        int c = tid + i * 256;                 // 512 bf16x8 chunks
        int h = c >> 3, dx = (c & 7) * 8;
        bf16x8 o;
        for (int j = 0; j < 8; j++) o[j] = Tb[dx + j][h];
        *(bf16x8*)&dst[(size_t)h * 1024 + dx] = o;
    }
}

// k3: lin_w [D][NH*H] f32 -> bf16 (already B^T layout for proj GEMM)
__global__ __launch_bounds__(256) void cvt_linw(const float* __restrict__ lw,
                                                bf16_t* __restrict__ lb) {
    int i = (blockIdx.x * 256 + threadIdx.x) * 4;
    float4 v = *(const float4*)&lw[i];
    bf16_t* o = &lb[i];
    o[0] = (bf16_t)v.x; o[1] = (bf16_t)v.y; o[2] = (bf16_t)v.z; o[3] = (bf16_t)v.w;
}

// ---------------------------------------------------------------------------
// Shared GEMM for stage A (logits) and stage D (output proj).
// C[8192,1024] = A[8192,1024] @ Bt[1024,1024]^T, 128x128 tile, 4 waves (2x2).
// m97-style: global_load_lds width=16 into LINEAR [128][64] LDS with the
// rule-#21 both-sides XOR swizzle (byte ^= (row&7)<<4).
// mode 0: out_bf[idx] = bf16(acc)
// mode 1: out_f[idx] = acc + bias[col] + xres[idx]
__global__ __launch_bounds__(256) void gemm_ad(const bf16_t* __restrict__ A,
                                               const bf16_t* __restrict__ Bt,
                                               int mode,
                                               bf16_t* __restrict__ out_bf,
                                               float* __restrict__ out_f,
                                               const float* __restrict__ bias,
                                               const float* __restrict__ xres) {
    __shared__ __attribute__((aligned(16))) bf16_t As[128][64];
    __shared__ __attribute__((aligned(16))) bf16_t Bs[128][64];
    int tid = threadIdx.x;
    int bm = blockIdx.x * 128, bn = blockIdx.y * 128;
    int wave = tid >> 6, lane = tid & 63;
    int wm = (wave >> 1) * 64, wn = (wave & 1) * 64;
    int l15 = lane & 15, quad = lane >> 4;
    floatx4 acc[4][4] = {};
    int srow = lane >> 3;
    int scol = 8 * ((lane & 7) ^ srow);
    const bf16_t* abase = A  + (size_t)bm * 1024;
    const bf16_t* bbase = Bt + (size_t)bn * 1024;
    for (int kt = 0; kt < 1024; kt += 64) {
        __syncthreads();
        for (int i = 0; i < 4; i++) {
            int seg = wave * 4 + i;
            int r = seg * 8 + srow;
            GLD_LDS16(abase + (size_t)r * 1024 + kt + scol, (char*)&As[0][0] + seg * 1024);
            GLD_LDS16(bbase + (size_t)r * 1024 + kt + scol, (char*)&Bs[0][0] + seg * 1024);
        }
        __syncthreads();
        for (int ks = 0; ks < 2; ks++) {
            bf16x8 af[4], bfr[4];
            for (int mi = 0; mi < 4; mi++) {
                int row = wm + mi * 16 + l15;
                int cb = (ks * 64 + quad * 16) ^ ((row & 7) << 4);
                af[mi] = *(const bf16x8*)((const char*)&As[row][0] + cb);
            }
            for (int ni = 0; ni < 4; ni++) {
                int row = wn + ni * 16 + l15;
                int cb = (ks * 64 + quad * 16) ^ ((row & 7) << 4);
                bfr[ni] = *(const bf16x8*)((const char*)&Bs[row][0] + cb);
            }
            for (int mi = 0; mi < 4; mi++)
                for (int ni = 0; ni < 4; ni++)
                    acc[mi][ni] = __builtin_amdgcn_mfma_f32_16x16x32_bf16(af[mi], bfr[ni], acc[mi][ni], 0, 0, 0);
        }
    }
    for (int mi = 0; mi < 4; mi++)
        for (int ni = 0; ni < 4; ni++) {
            int col = bn + wn + ni * 16 + l15;
            for (int r = 0; r < 4; r++) {
                int row = bm + wm + mi * 16 + quad * 4 + r;
                size_t idx = (size_t)row * 1024 + col;
                float v = acc[mi][ni][r];
                if (mode == 0) out_bf[idx] = (bf16_t)v;
                else           out_f[idx] = v + bias[col] + xres[idx];
            }
        }
}

// ---------------------------------------------------------------------------
// k5: logits [b*1024+s][n*64+h] -> vt [(n*8+b)*64+h][s]  (V^T per head)
__global__ __launch_bounds__(256) void transpose_v(const bf16_t* __restrict__ logits,
                                                   bf16_t* __restrict__ vt) {
    __shared__ __attribute__((aligned(16))) bf16_t T[64][72];
    int nb = blockIdx.y;
    int n = nb >> 3, b = nb & 7;
    int s0 = blockIdx.x * 64;
    int tid = threadIdx.x;
    const bf16_t* src = logits + (size_t)(b * 1024 + s0) * 1024 + n * 64;
    for (int i = 0; i < 2; i++) {
        int c = tid + i * 256;
        int r = c >> 3, c8 = (c & 7) * 8;
        *(bf16x8*)&T[r][c8] = *(const bf16x8*)&src[(size_t)r * 1024 + c8];
    }
    __syncthreads();
    bf16_t* dst = vt + (size_t)nb * 64 * 1024 + s0;
    for (int i = 0; i < 2; i++) {
        int c = tid + i * 256;
        int h = c >> 3, sx = (c & 7) * 8;
        bf16x8 o;
        for (int j = 0; j < 8; j++) o[j] = T[sx + j][h];
        *(bf16x8*)&dst[(size_t)h * 1024 + sx] = o;
    }
}

// ---------------------------------------------------------------------------
// Fused scores -> softmax -> PV.  Per WG: one (n,b) head, 64 query rows.
// Q held in registers (2 bf16x8 per lane); K/V reg-staged with T14
// async-split (issue tile t+1 loads before computing tile t).
// LDS = Ks 18K + Vts 17K + Pl 17K = 52 KB -> 3 WG/CU.
// grid: x = row-tile (16 x 64 rows), y = nb (128).
__global__ __launch_bounds__(256, 3) void fused_attn(const bf16_t* __restrict__ logits,
                                                     const bf16_t* __restrict__ vt,
                                                     float* __restrict__ attn,
                                                     bf16_t* __restrict__ outh) {
    __shared__ __attribute__((aligned(16))) bf16_t Ks[128][72];
    __shared__ __attribute__((aligned(16))) bf16_t Vts[64][136];
    __shared__ __attribute__((aligned(16))) bf16_t Pl[4][16][136];
    int nb = blockIdx.y;
    int n = nb >> 3, b = nb & 7;
    int r0 = blockIdx.x * 64;
    int tid = threadIdx.x;
    int wave = tid >> 6, lane = tid & 63;
    int l15 = lane & 15, quad = lane >> 4;
    const bf16_t* kbase = logits + (size_t)(b * 1024) * 1024 + n * 64;
    const bf16_t* vbase = vt + (size_t)nb * 64 * 1024;

    // Q fragments in registers: A-frag row = lane&15, k = quad*8 + j
    bf16x8 qf[2];
    {
        const bf16_t* qrow = logits + (size_t)(b * 1024 + r0 + wave * 16 + l15) * 1024 + n * 64;
        qf[0] = *(const bf16x8*)&qrow[quad * 8];
        qf[1] = *(const bf16x8*)&qrow[32 + quad * 8];
    }

    // staging chunk coords (K tile: 128 rows x 64 cols, 1024 bf16x8 chunks)
    int kr[4], kc[4], vh[4], vc[4];
    for (int i = 0; i < 4; i++) {
        int c = tid + i * 256;
        kr[i] = c >> 3;  kc[i] = (c & 7) * 8;
        vh[i] = c >> 4;  vc[i] = (c & 15) * 8;
    }

    bf16x8 kreg[4], vreg[4];
    // ---------------- pass 1: row sums of exp ----------------
    for (int i = 0; i < 4; i++)
        kreg[i] = *(const bf16x8*)&kbase[(size_t)kr[i] * 1024 + kc[i]];
    float rsum[4] = {0.f, 0.f, 0.f, 0.f};
    for (int t0 = 0; t0 < 1024; t0 += 128) {
        __syncthreads();
        for (int i = 0; i < 4; i++) *(bf16x8*)&Ks[kr[i]][kc[i]] = kreg[i];
        if (t0 < 896)
            for (int i = 0; i < 4; i++)
                kreg[i] = *(const bf16x8*)&kbase[(size_t)(t0 + 128 + kr[i]) * 1024 + kc[i]];
        __syncthreads();
        floatx4 acc[8] = {};
        for (int ks = 0; ks < 2; ks++) {
            for (int ni = 0; ni < 8; ni++) {
                bf16x8 bf = *(const bf16x8*)&Ks[ni * 16 + l15][ks * 32 + quad * 8];
                acc[ni] = __builtin_amdgcn_mfma_f32_16x16x32_bf16(qf[ks], bf, acc[ni], 0, 0, 0);
            }
        }
        for (int ni = 0; ni < 8; ni++)
            for (int r = 0; r < 4; r++)
                rsum[r] += __expf(acc[ni][r] * 0.125f);
    }
    // issue pass-2 prologue loads before the reduce (overlap)
    for (int i = 0; i < 4; i++) {
        kreg[i] = *(const bf16x8*)&kbase[(size_t)kr[i] * 1024 + kc[i]];
        vreg[i] = *(const bf16x8*)&vbase[(size_t)vh[i] * 1024 + vc[i]];
    }
    for (int off = 1; off < 16; off <<= 1)
        for (int r = 0; r < 4; r++) rsum[r] += __shfl_xor(rsum[r], off);
    float inv[4];
    for (int r = 0; r < 4; r++) inv[r] = 1.0f / rsum[r];

    // ---------------- pass 2: normalize, write attn, PV ----------------
    floatx4 accpv[4] = {};
    float* obase = attn + (size_t)nb * 1048576 + (size_t)r0 * 1024;
    for (int t0 = 0; t0 < 1024; t0 += 128) {
        __syncthreads();
        for (int i = 0; i < 4; i++) *(bf16x8*)&Ks[kr[i]][kc[i]] = kreg[i];
        for (int i = 0; i < 4; i++) *(bf16x8*)&Vts[vh[i]][vc[i]] = vreg[i];
        if (t0 < 896)
            for (int i = 0; i < 4; i++) {
                kreg[i] = *(const bf16x8*)&kbase[(size_t)(t0 + 128 + kr[i]) * 1024 + kc[i]];
                vreg[i] = *(const bf16x8*)&vbase[(size_t)vh[i] * 1024 + t0 + 128 + vc[i]];
            }
        __syncthreads();
        floatx4 acc[8] = {};
        for (int ks = 0; ks < 2; ks++) {
            for (int ni = 0; ni < 8; ni++) {
                bf16x8 bf = *(const bf16x8*)&Ks[ni * 16 + l15][ks * 32 + quad * 8];
                acc[ni] = __builtin_amdgcn_mfma_f32_16x16x32_bf16(qf[ks], bf, acc[ni], 0, 0, 0);
            }
        }
        for (int ni = 0; ni < 8; ni++)
            for (int r = 0; r < 4; r++) {
                float p = __expf(acc[ni][r] * 0.125f) * inv[r];
                int sl = wave * 16 + quad * 4 + r;
                obase[(size_t)sl * 1024 + t0 + ni * 16 + l15] = p;
                Pl[wave][quad * 4 + r][ni * 16 + l15] = (bf16_t)p;
            }
        for (int ks2 = 0; ks2 < 4; ks2++) {
            bf16x8 pa = *(const bf16x8*)&Pl[wave][l15][ks2 * 32 + quad * 8];
            for (int ni = 0; ni < 4; ni++) {
                bf16x8 bv = *(const bf16x8*)&Vts[ni * 16 + l15][ks2 * 32 + quad * 8];
                accpv[ni] = __builtin_amdgcn_mfma_f32_16x16x32_bf16(pa, bv, accpv[ni], 0, 0, 0);
            }
        }
    }
    for (int ni = 0; ni < 4; ni++) {
        int h = ni * 16 + l15;
        for (int r = 0; r < 4; r++) {
            int s = r0 + wave * 16 + quad * 4 + r;
            outh[(size_t)(b * 1024 + s) * 1024 + n * 64 + h] = (bf16_t)accpv[ni][r];
        }
    }
}

// ---------------------------------------------------------------------------
// k10: LayerNorm over D=1024. grid = 8192 rows.
__global__ __launch_bounds__(256) void ln_kernel(const float* __restrict__ z,
                                                 const float* __restrict__ g,
                                                 const float* __restrict__ beta,
                                                 float* __restrict__ y) {
    size_t row = blockIdx.x;
    const float* p = z + row * 1024;
    int tid = threadIdx.x;
    float4 v = *(const float4*)&p[tid * 4];
    float s1 = v.x + v.y + v.z + v.w;
    float s2 = v.x * v.x + v.y * v.y + v.z * v.z + v.w * v.w;
    for (int off = 32; off; off >>= 1) {
        s1 += __shfl_xor(s1, off);
        s2 += __shfl_xor(s2, off);
    }
    __shared__ float r1[4], r2[4];
    int wave = tid >> 6;
    if ((tid & 63) == 0) { r1[wave] = s1; r2[wave] = s2; }
    __syncthreads();
    s1 = r1[0] + r1[1] + r1[2] + r1[3];
    s2 = r2[0] + r2[1] + r2[2] + r2[3];
    float mu = s1 * (1.0f / 1024.0f);
    float var = s2 * (1.0f / 1024.0f) - mu * mu;
    float rstd = rsqrtf(var + 1e-5f);
    float4 gv = *(const float4*)&g[tid * 4];
    float4 bv = *(const float4*)&beta[tid * 4];
    float4 o;
    o.x = (v.x - mu) * rstd * gv.x + bv.x;
    o.y = (v.y - mu) * rstd * gv.y + bv.y;
    o.z = (v.z - mu) * rstd * gv.z + bv.z;
    o.w = (v.w - mu) * rstd * gv.w + bv.w;
    *(float4*)&y[row * 1024 + tid * 4] = o;
}

// ---------------------------------------------------------------------------
extern "C" void kernel_launch(void* const* d_in, const int* in_sizes, int n_in,
                              void* d_out, int out_size, void* d_ws, size_t ws_size,
                              hipStream_t stream) {
    const float* x     = (const float*)d_in[0];  // [8,1024,1024]
    const float* w     = (const float*)d_in[1];  // [16,1024,64]
    const float* lw    = (const float*)d_in[2];  // [1024,1024]
    const float* lb    = (const float*)d_in[3];  // [1024]
    const float* lg    = (const float*)d_in[4];  // [1024]
    const float* lbeta = (const float*)d_in[5];  // [1024]
    float* y    = (float*)d_out;                 // [8,1024,1024]
    float* attn = y + 8388608;                   // [128,1024,1024]

    // Workspace overlay (54.5 MB total):
    //   [0,16M)     xb (stage A input)   -> reused as outh (fused output)
    //   [16M,18M)   w_t
    //   [18M,20M)   lin_w bf16
    //   [20M,37M)   logits bf16          -> reused as lower half of z
    //   [37M,53M)   vt                   -> reused as upper half of z
    char* ws = (char*)d_ws;
    bf16_t* xb     = (bf16_t*)(ws);
    bf16_t* outh   = (bf16_t*)(ws);
    bf16_t* wt     = (bf16_t*)(ws + 16777216);
    bf16_t* lwb    = (bf16_t*)(ws + 18874368);
    bf16_t* logits = (bf16_t*)(ws + 20971520);
    float*  z      = (float*)(ws + 20971520);
    bf16_t* vt     = (bf16_t*)(ws + 37748736);

    hipLaunchKernelGGL(cvt_x,        dim3(8192),       dim3(256), 0, stream, x, xb);
    hipLaunchKernelGGL(prep_w,       dim3(16, 16),     dim3(256), 0, stream, w, wt);
    hipLaunchKernelGGL(cvt_linw,     dim3(1024),       dim3(256), 0, stream, lw, lwb);
    hipLaunchKernelGGL(gemm_ad,      dim3(64, 8),      dim3(256), 0, stream,
                       xb, wt, 0, logits, (float*)nullptr, (const float*)nullptr, (const float*)nullptr);
    hipLaunchKernelGGL(transpose_v,  dim3(16, 128),    dim3(256), 0, stream, logits, vt);
    hipLaunchKernelGGL(fused_attn,   dim3(16, 128),    dim3(256), 0, stream, logits, vt, attn, outh);
    hipLaunchKernelGGL(gemm_ad,      dim3(64, 8),      dim3(256), 0, stream,
                       outh, lwb, 1, (bf16_t*)nullptr, z, lb, x);
    hipLaunchKernelGGL(ln_kernel,    dim3(8192),       dim3(256), 0, stream, z, lg, lbeta, y);
}